// Round 11
// baseline (257.671 us; speedup 1.0000x reference)
//
#include <hip/hip_runtime.h>
#include <hip/hip_fp16.h>
#include <math.h>

#define WAVE  64
#define SPAD  128    // padded score cols (K=100 -> 128)
#define NW    8      // waves per block in k_fused
#define WCOLS 112    // padded W^T cols staged fp16 (7 col-tiles of 16)

typedef float    f32x4 __attribute__((ext_vector_type(4)));
typedef _Float16 f16x8 __attribute__((ext_vector_type(8)));

#define MFMA16 __builtin_amdgcn_mfma_f32_16x16x32_f16

__device__ __forceinline__ f16x8 cvt8(f32x4 a, f32x4 b) {
    f16x8 r;
    r[0]=(_Float16)a.x; r[1]=(_Float16)a.y; r[2]=(_Float16)a.z; r[3]=(_Float16)a.w;
    r[4]=(_Float16)b.x; r[5]=(_Float16)b.y; r[6]=(_Float16)b.z; r[7]=(_Float16)b.w;
    return r;
}

// fp32 convert-and-accumulate of one 16B chunk (8 halves), weighted
#define ACC8T(qq,s,A0,A1,A2,A3,A4,A5,A6,A7) {                                \
    const __half2* hh_ = (const __half2*)&(qq);                              \
    float2 f0_=__half22float2(hh_[0]), f1_=__half22float2(hh_[1]);           \
    float2 f2_=__half22float2(hh_[2]), f3_=__half22float2(hh_[3]);           \
    A0+=(s)*f0_.x; A1+=(s)*f0_.y; A2+=(s)*f1_.x; A3+=(s)*f1_.y;              \
    A4+=(s)*f2_.x; A5+=(s)*f2_.y; A6+=(s)*f3_.x; A7+=(s)*f3_.y; }

// depth-1 fp16 pair-add over 2 token-rows, then one fp32 convert-add
#define TREE2T(qa,qb,A0,A1,A2,A3,A4,A5,A6,A7) {                              \
    const __half2* p0_ = (const __half2*)&(qa);                              \
    const __half2* p1_ = (const __half2*)&(qb);                              \
    __half2 s0_=__hadd2(p0_[0],p1_[0]);                                      \
    __half2 s1_=__hadd2(p0_[1],p1_[1]);                                      \
    __half2 s2_=__hadd2(p0_[2],p1_[2]);                                      \
    __half2 s3_=__hadd2(p0_[3],p1_[3]);                                      \
    float2 f0_=__half22float2(s0_), f1_=__half22float2(s1_);                 \
    float2 f2_=__half22float2(s2_), f3_=__half22float2(s3_);                 \
    A0+=f0_.x; A1+=f0_.y; A2+=f1_.x; A3+=f1_.y;                              \
    A4+=f2_.x; A5+=f2_.y; A6+=f3_.x; A7+=f3_.y; }

// ---- quarter-group (16-lane) S-row gather steps: 4 tokens per wave-load ----
#define QSTEP2(idxv,j0,A0,A1,A2,A3,A4,A5,A6,A7) {                            \
    int r0_ = __shfl(idxv, (j0) + qtr);                                      \
    int r1_ = __shfl(idxv, (j0) + 4 + qtr);                                  \
    float4 q0_ = S16[(size_t)r0_ * 16 + c];                                  \
    float4 q1_ = S16[(size_t)r1_ * 16 + c];                                  \
    TREE2T(q0_, q1_, A0,A1,A2,A3,A4,A5,A6,A7); }
#define QSTEP1(idxv,j0,A0,A1,A2,A3,A4,A5,A6,A7) {                            \
    int r0_ = __shfl(idxv, (j0) + qtr);                                      \
    float4 q0_ = S16[(size_t)r0_ * 16 + c];                                  \
    ACC8T(q0_, 1.0f, A0,A1,A2,A3,A4,A5,A6,A7); }
#define QTAIL(idxv,jv,nn,A0,A1,A2,A3,A4,A5,A6,A7) if ((jv) < (nn)) {         \
    int srcl_ = (jv) + qtr;                                                  \
    int rr_ = __shfl(idxv, (srcl_ < (nn)) ? srcl_ : ((nn) - 1));             \
    float s_ = (srcl_ < (nn)) ? 1.0f : 0.0f;                                 \
    float4 q_ = S16[(size_t)rr_ * 16 + c];                                   \
    ACC8T(q_, s_, A0,A1,A2,A3,A4,A5,A6,A7); }

// quarter-merge (xor 16,32) + mean
#define QFIN(A0,A1,A2,A3,A4,A5,A6,A7,nv) {                                   \
    A0+=__shfl_xor(A0,16); A1+=__shfl_xor(A1,16);                            \
    A2+=__shfl_xor(A2,16); A3+=__shfl_xor(A3,16);                            \
    A4+=__shfl_xor(A4,16); A5+=__shfl_xor(A5,16);                            \
    A6+=__shfl_xor(A6,16); A7+=__shfl_xor(A7,16);                            \
    A0+=__shfl_xor(A0,32); A1+=__shfl_xor(A1,32);                            \
    A2+=__shfl_xor(A2,32); A3+=__shfl_xor(A3,32);                            \
    A4+=__shfl_xor(A4,32); A5+=__shfl_xor(A5,32);                            \
    A6+=__shfl_xor(A6,32); A7+=__shfl_xor(A7,32);                            \
    float inv_ = 1.0f/(float)(nv);                                           \
    A0*=inv_; A1*=inv_; A2*=inv_; A3*=inv_;                                  \
    A4*=inv_; A5*=inv_; A6*=inv_; A7*=inv_; }

// selected score = mean-S-row[rt] (one element pick + 16-lane reduce)
#define SELP(A0,A1,A2,A3,A4,A5,A6,A7,pvar) {                                 \
    float t_ = (rlo==0)?A0:(rlo==1)?A1:(rlo==2)?A2:(rlo==3)?A3:              \
               (rlo==4)?A4:(rlo==5)?A5:(rlo==6)?A6:A7;                       \
    pvar = (c == rhi) ? t_ : 0.0f;                                           \
    pvar += __shfl_xor(pvar,1); pvar += __shfl_xor(pvar,2);                  \
    pvar += __shfl_xor(pvar,4); pvar += __shfl_xor(pvar,8); }

// online-softmax update of (mx,sum,z0..z7)
#define ONLUPD(pv,A0,A1,A2,A3,A4,A5,A6,A7) {                                 \
    float nmx_=fmaxf(mx,pv);                                                 \
    float sc_=__expf(mx-nmx_), w_=__expf((pv)-nmx_);                         \
    sum=sum*sc_+w_;                                                          \
    z0=z0*sc_+w_*A0; z1=z1*sc_+w_*A1; z2=z2*sc_+w_*A2; z3=z3*sc_+w_*A3;      \
    z4=z4*sc_+w_*A4; z5=z5*sc_+w_*A5; z6=z6*sc_+w_*A6; z7=z7*sc_+w_*A7;      \
    mx=nmx_; }

// ---------------------------------------------------------------------------
// K0 (k_w): argmax + W^T fp32->fp16 to GLOBAL (wh[112][256], cols K..111
// zero). Separate launch so k_gemm blocks see wh ready.
// ---------------------------------------------------------------------------
__global__ __launch_bounds__(256) void k_w(const float* __restrict__ tt,
                                           const float* __restrict__ lw,
                                           int* __restrict__ type_idx,
                                           __half* __restrict__ wh,
                                           int B, int K, int D, int nArgBlk) {
    int bx = blockIdx.x;
    if (bx < nArgBlk) {
        int wid  = threadIdx.x >> 6;
        int lane = threadIdx.x & 63;
        int b = bx * 4 + wid;
        if (b >= B) return;
        float best = -INFINITY;
        int   bi   = 0x7fffffff;
        for (int k = lane; k < K; k += WAVE) {
            float v = tt[(size_t)b * K + k];
            if (v > best) { best = v; bi = k; }
        }
        for (int off = 32; off > 0; off >>= 1) {
            float ov = __shfl_down(best, off);
            int   oi = __shfl_down(bi, off);
            if (ov > best || (ov == best && oi < bi)) { best = ov; bi = oi; }
        }
        if (lane == 0) type_idx[b] = bi;
    } else {
        int e = ((bx - nArgBlk) * 256 + (int)threadIdx.x) * 4;
        int total = WCOLS * 256;
        #pragma unroll
        for (int i = 0; i < 4; ++i) {
            int idx = e + i;
            if (idx >= total) break;
            int col = idx >> 8;
            int k   = idx & 255;
            wh[idx] = (col < K) ? __float2half(lw[(size_t)col * D + k])
                                : __half(0.0f);
        }
    }
}

// ---------------------------------------------------------------------------
// K1 (k_gemm) v3: S = we @ W^T fp16 [V][SPAD] via MFMA 16x16x32_f16.
// R10 was latency-bound (MfmaUtil 3%, occ 22%): 782 blocks = 12 waves/CU
// grid cap, shallow prefetch, 64 scalar half stores/lane. v3:
//  - ONE 16-row strip per wave: 6250 waves / 1563 blocks -> 24 waves/CU cap.
//  - 4 k-chunks of A in flight (fully unrolled a[8][2], static indices).
//  - SWAPPED MFMA roles (af=wh, bf=we). Both frags use the identical
//    (lane&15 -> index, lane>>4 -> k-group) map (R9/R10 HW-verified), so the
//    swap transposes D: lane now holds 4 CONSECUTIVE S-cols of ONE row ->
//    stores become 7+1 vectorized 8B stores (was 64 scalar 2B).
//  - we loads nontemporal (streaming 102MB; keep L2 for wh + S).
// ---------------------------------------------------------------------------
__global__ __launch_bounds__(256) void k_gemm(const float* __restrict__ we,
                                              const __half* __restrict__ wh,
                                              __half* __restrict__ S,
                                              int V) {
    int tid  = threadIdx.x;
    int wid  = tid >> 6;
    int lane = tid & 63;
    int nstrip = V >> 4;                     // 6250 (V = 100000)
    int strip  = blockIdx.x * 4 + wid;
    if (strip >= nstrip) return;
    int rb  = strip << 4;                    // 16 rows
    int r16 = lane & 15;
    int grp = lane >> 4;                     // k-group 0..3

    // my A-source slice of we: row rb+r16, chunk c at float4 index c*8+{0,1}
    const f32x4* wrow = (const f32x4*)(we + (size_t)(rb + r16) * 256) + grp * 2;
    const _Float16* whh = (const _Float16*)wh;

    f32x4 acc[7];
    #pragma unroll
    for (int ct = 0; ct < 7; ++ct) acc[ct] = (f32x4){0.f, 0.f, 0.f, 0.f};

    f32x4 a[8][2];
    #pragma unroll
    for (int cc = 0; cc < 4; ++cc) {         // prefetch chunks 0..3
        a[cc][0] = __builtin_nontemporal_load(&wrow[cc * 8]);
        a[cc][1] = __builtin_nontemporal_load(&wrow[cc * 8 + 1]);
    }

    #pragma unroll
    for (int cc = 0; cc < 8; ++cc) {         // 8 k-chunks of 32
        if (cc < 4) {                        // keep 4 chunks in flight
            a[cc + 4][0] = __builtin_nontemporal_load(&wrow[(cc + 4) * 8]);
            a[cc + 4][1] = __builtin_nontemporal_load(&wrow[(cc + 4) * 8 + 1]);
        }
        f16x8 bf = cvt8(a[cc][0], a[cc][1]); // we fragment (B operand)
        int ke = cc * 32 + grp * 8;
        #pragma unroll
        for (int ct = 0; ct < 7; ++ct) {     // wh fragment (A operand)
            f16x8 af = *(const f16x8*)(whh + (size_t)(ct * 16 + r16) * 256 + ke);
            acc[ct] = MFMA16(af, bf, acc[ct], 0, 0, 0);
        }
    }

    // store: lane holds S[rb+r16][ct*16 + grp*4 + i], i=0..3 -> one 8B store
    __half* srow = S + (size_t)(rb + r16) * SPAD;
    #pragma unroll
    for (int ct = 0; ct < 7; ++ct) {
        __half2 h0 = __float22half2_rn(make_float2(acc[ct][0], acc[ct][1]));
        __half2 h1 = __float22half2_rn(make_float2(acc[ct][2], acc[ct][3]));
        uint2 u;
        u.x = *reinterpret_cast<const unsigned int*>(&h0);
        u.y = *reinterpret_cast<const unsigned int*>(&h1);
        *reinterpret_cast<uint2*>(srow + ct * 16 + grp * 4) = u;
    }
    *reinterpret_cast<uint2*>(srow + 112 + grp * 4) = make_uint2(0u, 0u);
}

// ---------------------------------------------------------------------------
// K2 (fused): UNCHANGED (R8-R10, ~50us). One block (512 thr = 8 waves) per
// bag; wave owns two adjacent mention chains (16 chains/bag, zero
// divergence). Gathers 256B S-rows (quarter-group: 4 tokens/wave-load).
// sel = one-hot pick from mean-S-row; out = online-softmax accumulation of
// mean-S-rows -- no final projection.
// ---------------------------------------------------------------------------
__global__ __launch_bounds__(512, 8) void k_fused(const int* __restrict__ fs,
                                                  const int* __restrict__ offs,
                                                  const int* __restrict__ scope,
                                                  const int* __restrict__ type_idx,
                                                  const __half* __restrict__ S,
                                                  float* __restrict__ out,
                                                  int B, int M, int T, int K) {
    __shared__ float s_acc[NW][SPAD];
    __shared__ float s_stats[NW][2];
    __shared__ float s_be[SPAD];

    int b    = blockIdx.x;
    int tid  = threadIdx.x;
    int wid  = tid >> 6;
    int lane = tid & 63;
    int c    = lane & 15;     // 16B chunk within 256B S-row
    int qtr  = lane >> 4;     // quarter: token j+qtr of each 4-token step

    int m0 = scope[b];
    int m1 = scope[b + 1];
    int rt  = type_idx[b];
    int rhi = rt >> 3, rlo = rt & 7;

    const float4* S16 = (const float4*)S;   // 16 chunks per 256B row

    float mx = -INFINITY, sum = 0.f;
    float z0=0,z1=0,z2=0,z3=0,z4=0,z5=0,z6=0,z7=0;

    for (int mA = m0 + wid * 2; mA < m1; mA += 2 * NW) {
        int mB = mA + 1;
        bool hasB = (mB < m1);                  // wave-uniform

        int tA0 = offs[mA];
        int tA1 = (mA + 1 < M) ? offs[mA + 1] : T;
        int tB0 = tA1;                          // offs[mB] == tA1 when hasB
        int tB1 = hasB ? ((mB + 1 < M) ? offs[mB + 1] : T) : tA1;

        int nA = tA1 - tA0;
        int nB = tB1 - tB0;                     // 0 when !hasB

        float aA0=0,aA1=0,aA2=0,aA3=0,aA4=0,aA5=0,aA6=0,aA7=0;
        float aB0=0,aB1=0,aB2=0,aB3=0,aB4=0,aB5=0,aB6=0,aB7=0;

        int cA = tA0, cB = tB0;
        while (cA < tA1 || cB < tB1) {
            int nnA = tA1 - cA; nnA = (nnA > 64) ? 64 : nnA; if (nnA < 0) nnA = 0;
            int nnB = tB1 - cB; nnB = (nnB > 64) ? 64 : nnB; if (nnB < 0) nnB = 0;
            int idxA = (lane < nnA) ? fs[cA + lane] : 0;
            int idxB = (lane < nnB) ? fs[cB + lane] : 0;

            int jA = 0, jB = 0;
            for (; jA + 8 <= nnA && jB + 8 <= nnB; jA += 8, jB += 8) {
                QSTEP2(idxA, jA, aA0,aA1,aA2,aA3,aA4,aA5,aA6,aA7);
                QSTEP2(idxB, jB, aB0,aB1,aB2,aB3,aB4,aB5,aB6,aB7);
            }
            for (; jA + 8 <= nnA; jA += 8)
                QSTEP2(idxA, jA, aA0,aA1,aA2,aA3,aA4,aA5,aA6,aA7);
            for (; jB + 8 <= nnB; jB += 8)
                QSTEP2(idxB, jB, aB0,aB1,aB2,aB3,aB4,aB5,aB6,aB7);
            for (; jA + 4 <= nnA; jA += 4)
                QSTEP1(idxA, jA, aA0,aA1,aA2,aA3,aA4,aA5,aA6,aA7);
            for (; jB + 4 <= nnB; jB += 4)
                QSTEP1(idxB, jB, aB0,aB1,aB2,aB3,aB4,aB5,aB6,aB7);
            QTAIL(idxA, jA, nnA, aA0,aA1,aA2,aA3,aA4,aA5,aA6,aA7);
            QTAIL(idxB, jB, nnB, aB0,aB1,aB2,aB3,aB4,aB5,aB6,aB7);
            cA += nnA; cB += nnB;
        }

        // epilogue: quarter-merge + mean + one-hot score + online update
        {
            QFIN(aA0,aA1,aA2,aA3,aA4,aA5,aA6,aA7, nA);
            float pA; SELP(aA0,aA1,aA2,aA3,aA4,aA5,aA6,aA7, pA);
            ONLUPD(pA, aA0,aA1,aA2,aA3,aA4,aA5,aA6,aA7);
        }
        if (hasB) {
            QFIN(aB0,aB1,aB2,aB3,aB4,aB5,aB6,aB7, nB);
            float pB; SELP(aB0,aB1,aB2,aB3,aB4,aB5,aB6,aB7, pB);
            ONLUPD(pB, aB0,aB1,aB2,aB3,aB4,aB5,aB6,aB7);
        }
    }

    // ---- deposit per-wave state (lanes 0..15 own dims 8c..8c+7) ----
    if (lane < 16) {
        ((float4*)s_acc[wid])[c * 2]     = make_float4(z0, z1, z2, z3);
        ((float4*)s_acc[wid])[c * 2 + 1] = make_float4(z4, z5, z6, z7);
    }
    if (lane == 0) { s_stats[wid][0] = mx; s_stats[wid][1] = sum; }
    __syncthreads();

    // ---- 8-way online-softmax merge; one S-col per thread (tid<SPAD) ----
    if (tid < SPAD) {
        float Mx = -INFINITY;
        #pragma unroll
        for (int g = 0; g < NW; ++g) Mx = fmaxf(Mx, s_stats[g][0]);
        float Ssum = 0.f, be = 0.f;
        #pragma unroll
        for (int g = 0; g < NW; ++g) {
            float e = __expf(s_stats[g][0] - Mx);
            Ssum += s_stats[g][1] * e;
            be   += s_acc[g][tid] * e;
        }
        s_be[tid] = be * (1.0f / Ssum);
    }
    __syncthreads();

    // ---- output: out[b][k] = s_be[k], k < K (no projection) ----
    float* ob = out + (size_t)b * K;
    if (2 * tid + 1 < K) {
        ((float2*)ob)[tid] = make_float2(s_be[2*tid], s_be[2*tid+1]);
    } else if (2 * tid < K) {
        ob[2*tid] = s_be[2*tid];
    }
}

// ---------------------------------------------------------------------------
extern "C" void kernel_launch(void* const* d_in, const int* in_sizes, int n_in,
                              void* d_out, int out_size, void* d_ws, size_t ws_size,
                              hipStream_t stream) {
    const int*   feature_seq = (const int*)d_in[0];
    const int*   offset_seq  = (const int*)d_in[1];
    const int*   scope       = (const int*)d_in[2];
    const float* typeTensor  = (const float*)d_in[3];
    const float* word_emb    = (const float*)d_in[4];
    const float* linear_w    = (const float*)d_in[5];
    float* out = (float*)d_out;

    const int T = in_sizes[0];
    const int M = in_sizes[1];
    const int B = in_sizes[2] - 1;
    const int K = in_sizes[3] / B;       // 100
    const int D = in_sizes[5] / K;       // 256
    const int V = in_sizes[4] / D;       // 100000

    // workspace carve-up: type_idx + wh (fp16 W^T) + S (25.6 MB)
    char* w = (char*)d_ws;
    auto align256 = [](size_t x) { return (x + 255) & ~(size_t)255; };
    int*    type_idx = (int*)w;    w += align256((size_t)B * sizeof(int));
    __half* wh       = (__half*)w; w += align256((size_t)WCOLS * 256 * sizeof(__half));
    __half* S        = (__half*)w; // V * SPAD halves

    // K0: argmax + W^T fp16 convert (ordering barrier = launch boundary)
    {
        int nArgBlk = (B + 3) / 4;
        int nWBlk   = (WCOLS * 256 + 1023) / 1024;
        k_w<<<nArgBlk + nWBlk, 256, 0, stream>>>(
            typeTensor, linear_w, type_idx, wh, B, K, D, nArgBlk);
    }
    // K1: S-GEMM (MFMA v3: strip/wave, 4-deep prefetch, vectorized stores)
    {
        int nStrip = (V + 15) / 16;
        int nBlk   = (nStrip + 3) / 4;
        k_gemm<<<nBlk, 256, 0, stream>>>(word_emb, wh, S, V);
    }
    // K2: fused mention mean-S + per-bag online softmax (direct K-dim output)
    {
        k_fused<<<B, 512, 0, stream>>>(feature_seq, offset_seq, scope, type_idx,
                                       S, out, B, M, T, K);
    }
}